// Round 1
// baseline (2150.336 us; speedup 1.0000x reference)
//
#include <hip/hip_runtime.h>
#include <hip/hip_bf16.h>

#define G 64
#define NVOX (G*G*G)
#define INC 32
#define OUTC 64
#define NCHUNK (NVOX/1024)   // 256 chunks for the two-level scan

// ---------------------------------------------------------------------------
// Stage 1: scatter-mean accumulation. 8 threads per point, 4 channels each.
// ---------------------------------------------------------------------------
__global__ __launch_bounds__(256) void scatter_kernel(
    const float* __restrict__ pts, const float* __restrict__ feats,
    float* __restrict__ sums, float* __restrict__ cnts, int npts)
{
    int tid = blockIdx.x * 256 + threadIdx.x;
    int p = tid >> 3;
    int q = tid & 7;
    if (p >= npts) return;

    float px = pts[p * 3 + 0];
    float py = pts[p * 3 + 1];
    float pz = pts[p * 3 + 2];
    int bx = (int)floorf(px);
    int by = (int)floorf(py);
    int bz = (int)floorf(pz);
    bx = min(max(bx, 0), G - 1);
    by = min(max(by, 0), G - 1);
    bz = min(max(bz, 0), G - 1);
    int fl = (bx * G + by) * G + bz;

    float4 f = ((const float4*)feats)[p * 8 + q];
    float* dst = sums + (size_t)fl * INC + q * 4;
    atomicAdd(dst + 0, f.x);
    atomicAdd(dst + 1, f.y);
    atomicAdd(dst + 2, f.z);
    atomicAdd(dst + 3, f.w);
    if (q == 0) atomicAdd(cnts + fl, 1.0f);
}

// ---------------------------------------------------------------------------
// Stage 2: sums -> means (in place). One thread per float4 (8 per voxel).
// ---------------------------------------------------------------------------
__global__ __launch_bounds__(256) void normalize_kernel(
    float* __restrict__ sums, const float* __restrict__ cnts)
{
    int t = blockIdx.x * 256 + threadIdx.x;   // over NVOX*8 float4s
    int v = t >> 3;
    float c = cnts[v];
    float inv = 1.0f / fmaxf(c, 1.0f);
    float4* s4 = (float4*)sums;
    float4 a = s4[t];
    a.x *= inv; a.y *= inv; a.z *= inv; a.w *= inv;
    s4[t] = a;
}

// ---------------------------------------------------------------------------
// Stage 3: dense 3x3x3 conv, 32 -> 64 channels, SAME padding.
// One thread per voxel, 64 fp32 accumulators; W reads are wave-uniform.
// ---------------------------------------------------------------------------
__global__ __launch_bounds__(256) void conv_kernel(
    const float* __restrict__ voxf, const float* __restrict__ Wc,
    float* __restrict__ convo)
{
    int v = blockIdx.x * 256 + threadIdx.x;
    int z = v & (G - 1);
    int y = (v >> 6) & (G - 1);
    int x = v >> 12;

    float acc[OUTC];
#pragma unroll
    for (int n = 0; n < OUTC; n++) acc[n] = 0.0f;

#pragma unroll 1
    for (int off = 0; off < 27; off++) {
        int dx = off / 9 - 1;
        int dy = (off / 3) % 3 - 1;
        int dz = off % 3 - 1;
        int nx = x + dx, ny = y + dy, nz = z + dz;
        if ((unsigned)nx >= (unsigned)G || (unsigned)ny >= (unsigned)G ||
            (unsigned)nz >= (unsigned)G)
            continue;
        int nb = v + dx * (G * G) + dy * G + dz;
        const float4* in4 = (const float4*)(voxf + (size_t)nb * INC);
        const float* Wo = Wc + off * (INC * OUTC);
#pragma unroll 1
        for (int k4 = 0; k4 < 8; k4++) {
            float4 f = in4[k4];
            const float* wr0 = Wo + (k4 * 4 + 0) * OUTC;
            const float* wr1 = Wo + (k4 * 4 + 1) * OUTC;
            const float* wr2 = Wo + (k4 * 4 + 2) * OUTC;
            const float* wr3 = Wo + (k4 * 4 + 3) * OUTC;
#pragma unroll
            for (int n = 0; n < OUTC; n++) {
                acc[n] += f.x * wr0[n];
                acc[n] += f.y * wr1[n];
                acc[n] += f.z * wr2[n];
                acc[n] += f.w * wr3[n];
            }
        }
    }

    float4* o4 = (float4*)(convo + (size_t)v * OUTC);
#pragma unroll
    for (int n = 0; n < OUTC / 4; n++)
        o4[n] = make_float4(acc[4 * n], acc[4 * n + 1], acc[4 * n + 2], acc[4 * n + 3]);
}

// ---------------------------------------------------------------------------
// Counting sort of points by voxel id (for gather cache locality).
// scan_local: per-1024-element chunk exclusive scan of cnts -> cursor,
//             chunk totals -> chunkSums.
// ---------------------------------------------------------------------------
__global__ __launch_bounds__(256) void scan_local_kernel(
    const float* __restrict__ cnts, int* __restrict__ cursor,
    int* __restrict__ chunkSums)
{
    __shared__ int lds[256];
    int base = blockIdx.x * 1024 + threadIdx.x * 4;
    int e0 = (int)cnts[base + 0];
    int e1 = (int)cnts[base + 1];
    int e2 = (int)cnts[base + 2];
    int e3 = (int)cnts[base + 3];
    int t0 = e0;
    int t1 = t0 + e1;
    int t2 = t1 + e2;
    int t3 = t2 + e3;                 // thread total
    lds[threadIdx.x] = t3;
    __syncthreads();
    int v = t3;
    for (int off = 1; off < 256; off <<= 1) {
        int n = (threadIdx.x >= off) ? lds[threadIdx.x - off] : 0;
        __syncthreads();
        v += n;
        lds[threadIdx.x] = v;
        __syncthreads();
    }
    int excl = v - t3;                // exclusive prefix of this thread
    cursor[base + 0] = excl;
    cursor[base + 1] = excl + t0;
    cursor[base + 2] = excl + t1;
    cursor[base + 3] = excl + t2;
    if (threadIdx.x == 255) chunkSums[blockIdx.x] = v;
}

// Single-block exclusive scan of the 256 chunk sums (in place).
__global__ __launch_bounds__(256) void scan_top_kernel(int* __restrict__ chunkSums)
{
    __shared__ int lds[256];
    int t = threadIdx.x;
    int x = chunkSums[t];
    lds[t] = x;
    __syncthreads();
    int v = x;
    for (int off = 1; off < 256; off <<= 1) {
        int n = (t >= off) ? lds[t - off] : 0;
        __syncthreads();
        v += n;
        lds[t] = v;
        __syncthreads();
    }
    chunkSums[t] = v - x;             // exclusive
}

// Add chunk offsets back into the per-voxel cursors.
__global__ __launch_bounds__(256) void scan_add_kernel(
    int* __restrict__ cursor, const int* __restrict__ chunkSums)
{
    int i = blockIdx.x * 256 + threadIdx.x;
    cursor[i] += chunkSums[i >> 10];
}

// Scatter point ids into voxel-sorted order.
__global__ __launch_bounds__(256) void sort_kernel(
    const float* __restrict__ pts, int* __restrict__ cursor,
    int* __restrict__ sorted, int npts)
{
    int p = blockIdx.x * 256 + threadIdx.x;
    if (p >= npts) return;
    float px = pts[p * 3 + 0];
    float py = pts[p * 3 + 1];
    float pz = pts[p * 3 + 2];
    int bx = (int)floorf(px);
    int by = (int)floorf(py);
    int bz = (int)floorf(pz);
    bx = min(max(bx, 0), G - 1);
    by = min(max(by, 0), G - 1);
    bz = min(max(bz, 0), G - 1);
    int fl = (bx * G + by) * G + bz;
    int idx = atomicAdd(&cursor[fl], 1);
    sorted[idx] = p;
}

// ---------------------------------------------------------------------------
// Stage 4: trilinear devoxelize + residual linear. One WAVE per point,
// lane = output channel. Points processed in voxel-sorted order so corner
// gathers from convo hit L1/L2; XCD-bijective block swizzle keeps contiguous
// sorted ranges within one XCD's L2.
// ---------------------------------------------------------------------------
#define WPAD 65

__global__ __launch_bounds__(256) void gather_kernel(
    const float* __restrict__ pts, const float* __restrict__ feats,
    const float* __restrict__ convo, const float* __restrict__ cnts,
    const float* __restrict__ Wl, const float* __restrict__ bl,
    const int* __restrict__ sorted,
    float* __restrict__ out, int npts)
{
    __shared__ float sW[INC * WPAD];   // sW[k*WPAD + c], c in [0,64)
    for (int i = threadIdx.x; i < INC * OUTC; i += 256) {
        int c = i >> 5;        // Wl layout [c][k]
        int k = i & 31;
        sW[k * WPAD + c] = Wl[i];
    }
    __syncthreads();

    // XCD-bijective swizzle: XCD x (= bid%8) owns a contiguous slice of the
    // sorted point range -> convo corner reuse stays inside one XCD's L2.
    int bid = blockIdx.x;
    int nwg = gridDim.x;
    int q = nwg >> 3, r = nwg & 7;
    int xcd = bid & 7, local = bid >> 3;
    int swz = (xcd < r) ? (xcd * (q + 1) + local)
                        : (r * (q + 1) + (xcd - r) * q + local);

    int slot = swz * 4 + (threadIdx.x >> 6);
    int c = threadIdx.x & 63;
    if (slot >= npts) return;
    int p = sorted[slot];

    float px = pts[p * 3 + 0];
    float py = pts[p * 3 + 1];
    float pz = pts[p * 3 + 2];
    int bx = (int)floorf(px);
    int by = (int)floorf(py);
    int bz = (int)floorf(pz);
    float fx = px - (float)bx;
    float fy = py - (float)by;
    float fz = pz - (float)bz;

    // ---- issue all 8 corner gathers first (independent loads, overlap VALU)
    float cw[8];
    float cv[8];
#pragma unroll
    for (int corner = 0; corner < 8; corner++) {
        int dx = (corner >> 2) & 1;
        int dy = (corner >> 1) & 1;
        int dz = corner & 1;
        int nx = bx + dx, ny = by + dy, nz = bz + dz;
        bool inb = ((unsigned)nx < (unsigned)G) && ((unsigned)ny < (unsigned)G) &&
                   ((unsigned)nz < (unsigned)G);
        int cx = min(max(nx, 0), G - 1);
        int cy = min(max(ny, 0), G - 1);
        int cz = min(max(nz, 0), G - 1);
        int fl = (cx * G + cy) * G + cz;
        float w = (dx ? fx : 1.0f - fx) * (dy ? fy : 1.0f - fy) * (dz ? fz : 1.0f - fz);
        if (!inb || !(cnts[fl] > 0.0f)) w = 0.0f;
        cw[corner] = w;
        cv[corner] = convo[(size_t)fl * OUTC + c];
    }

    float acc = bl[c];

    // residual linear: feats[p] @ Wl^T
    const float* fr = feats + (size_t)p * INC;
#pragma unroll
    for (int k = 0; k < INC; k++)
        acc += fr[k] * sW[k * WPAD + c];

#pragma unroll
    for (int corner = 0; corner < 8; corner++)
        acc += cw[corner] * cv[corner];

    out[(size_t)p * OUTC + c] = acc;
}

// ---------------------------------------------------------------------------
extern "C" void kernel_launch(void* const* d_in, const int* in_sizes, int n_in,
                              void* d_out, int out_size, void* d_ws, size_t ws_size,
                              hipStream_t stream)
{
    const float* pts   = (const float*)d_in[0];
    const float* feats = (const float*)d_in[1];
    const float* Wc    = (const float*)d_in[2];
    const float* Wl    = (const float*)d_in[3];
    const float* bl    = (const float*)d_in[4];
    float* out = (float*)d_out;
    int npts = in_sizes[0] / 3;

    // workspace layout
    float* sums  = (float*)d_ws;                    // NVOX*32
    float* cnts  = sums + (size_t)NVOX * INC;       // NVOX
    float* convo = cnts + NVOX;                     // NVOX*64

    // sort scratch ALIASES the sums region -- only touched after conv_kernel
    // has fully consumed sums (stream-ordered).
    int* cursor    = (int*)sums;                    // NVOX
    int* chunkSums = cursor + NVOX;                 // NCHUNK (=256)
    int* sorted    = chunkSums + NCHUNK;            // npts

    // zero scatter accumulators (sums + cnts = NVOX*33 floats)
    hipMemsetAsync(d_ws, 0, (size_t)NVOX * (INC + 1) * sizeof(float), stream);

    int scatter_blocks = (npts * 8 + 255) / 256;
    scatter_kernel<<<scatter_blocks, 256, 0, stream>>>(pts, feats, sums, cnts, npts);

    normalize_kernel<<<(NVOX * 8) / 256, 256, 0, stream>>>(sums, cnts);

    conv_kernel<<<NVOX / 256, 256, 0, stream>>>(sums, Wc, convo);

    // counting sort of points by voxel (scratch aliases sums; runs after conv)
    scan_local_kernel<<<NCHUNK, 256, 0, stream>>>(cnts, cursor, chunkSums);
    scan_top_kernel<<<1, 256, 0, stream>>>(chunkSums);
    scan_add_kernel<<<NVOX / 256, 256, 0, stream>>>(cursor, chunkSums);
    sort_kernel<<<(npts + 255) / 256, 256, 0, stream>>>(pts, cursor, sorted, npts);

    gather_kernel<<<(npts + 3) / 4, 256, 0, stream>>>(pts, feats, convo, cnts,
                                                      Wl, bl, sorted, out, npts);
}

// Round 2
// 1717.948 us; speedup vs baseline: 1.2517x; 1.2517x over previous
//
#include <hip/hip_runtime.h>
#include <hip/hip_bf16.h>

#define G 64
#define NVOX (G*G*G)
#define INC 32
#define OUTC 64
#define NCHUNK (NVOX/1024)   // 256 chunks for the two-level scan

// ---------------------------------------------------------------------------
// Stage 1: scatter-mean accumulation. 8 threads per point, 4 channels each.
// ---------------------------------------------------------------------------
__global__ __launch_bounds__(256) void scatter_kernel(
    const float* __restrict__ pts, const float* __restrict__ feats,
    float* __restrict__ sums, float* __restrict__ cnts, int npts)
{
    int tid = blockIdx.x * 256 + threadIdx.x;
    int p = tid >> 3;
    int q = tid & 7;
    if (p >= npts) return;

    float px = pts[p * 3 + 0];
    float py = pts[p * 3 + 1];
    float pz = pts[p * 3 + 2];
    int bx = (int)floorf(px);
    int by = (int)floorf(py);
    int bz = (int)floorf(pz);
    bx = min(max(bx, 0), G - 1);
    by = min(max(by, 0), G - 1);
    bz = min(max(bz, 0), G - 1);
    int fl = (bx * G + by) * G + bz;

    float4 f = ((const float4*)feats)[p * 8 + q];
    float* dst = sums + (size_t)fl * INC + q * 4;
    atomicAdd(dst + 0, f.x);
    atomicAdd(dst + 1, f.y);
    atomicAdd(dst + 2, f.z);
    atomicAdd(dst + 3, f.w);
    if (q == 0) atomicAdd(cnts + fl, 1.0f);
}

// ---------------------------------------------------------------------------
// Stage 2: sums -> means (in place). One thread per float4 (8 per voxel).
// ---------------------------------------------------------------------------
__global__ __launch_bounds__(256) void normalize_kernel(
    float* __restrict__ sums, const float* __restrict__ cnts)
{
    int t = blockIdx.x * 256 + threadIdx.x;   // over NVOX*8 float4s
    int v = t >> 3;
    float c = cnts[v];
    float inv = 1.0f / fmaxf(c, 1.0f);
    float4* s4 = (float4*)sums;
    float4 a = s4[t];
    a.x *= inv; a.y *= inv; a.z *= inv; a.w *= inv;
    s4[t] = a;
}

// ---------------------------------------------------------------------------
// Stage 3: dense 3x3x3 conv, 32 -> 64 channels, SAME padding.
// One thread per voxel, 64 fp32 accumulators; W reads are wave-uniform.
// ---------------------------------------------------------------------------
__global__ __launch_bounds__(256) void conv_kernel(
    const float* __restrict__ voxf, const float* __restrict__ Wc,
    float* __restrict__ convo)
{
    int v = blockIdx.x * 256 + threadIdx.x;
    int z = v & (G - 1);
    int y = (v >> 6) & (G - 1);
    int x = v >> 12;

    float acc[OUTC];
#pragma unroll
    for (int n = 0; n < OUTC; n++) acc[n] = 0.0f;

#pragma unroll 1
    for (int off = 0; off < 27; off++) {
        int dx = off / 9 - 1;
        int dy = (off / 3) % 3 - 1;
        int dz = off % 3 - 1;
        int nx = x + dx, ny = y + dy, nz = z + dz;
        if ((unsigned)nx >= (unsigned)G || (unsigned)ny >= (unsigned)G ||
            (unsigned)nz >= (unsigned)G)
            continue;
        int nb = v + dx * (G * G) + dy * G + dz;
        const float4* in4 = (const float4*)(voxf + (size_t)nb * INC);
        const float* Wo = Wc + off * (INC * OUTC);
#pragma unroll 1
        for (int k4 = 0; k4 < 8; k4++) {
            float4 f = in4[k4];
            const float* wr0 = Wo + (k4 * 4 + 0) * OUTC;
            const float* wr1 = Wo + (k4 * 4 + 1) * OUTC;
            const float* wr2 = Wo + (k4 * 4 + 2) * OUTC;
            const float* wr3 = Wo + (k4 * 4 + 3) * OUTC;
#pragma unroll
            for (int n = 0; n < OUTC; n++) {
                acc[n] += f.x * wr0[n];
                acc[n] += f.y * wr1[n];
                acc[n] += f.z * wr2[n];
                acc[n] += f.w * wr3[n];
            }
        }
    }

    float4* o4 = (float4*)(convo + (size_t)v * OUTC);
#pragma unroll
    for (int n = 0; n < OUTC / 4; n++)
        o4[n] = make_float4(acc[4 * n], acc[4 * n + 1], acc[4 * n + 2], acc[4 * n + 3]);
}

// ---------------------------------------------------------------------------
// Counting sort of points by voxel id (for gather cache locality).
// ---------------------------------------------------------------------------
__global__ __launch_bounds__(256) void scan_local_kernel(
    const float* __restrict__ cnts, int* __restrict__ cursor,
    int* __restrict__ chunkSums)
{
    __shared__ int lds[256];
    int base = blockIdx.x * 1024 + threadIdx.x * 4;
    int e0 = (int)cnts[base + 0];
    int e1 = (int)cnts[base + 1];
    int e2 = (int)cnts[base + 2];
    int e3 = (int)cnts[base + 3];
    int t0 = e0;
    int t1 = t0 + e1;
    int t2 = t1 + e2;
    int t3 = t2 + e3;                 // thread total
    lds[threadIdx.x] = t3;
    __syncthreads();
    int v = t3;
    for (int off = 1; off < 256; off <<= 1) {
        int n = (threadIdx.x >= off) ? lds[threadIdx.x - off] : 0;
        __syncthreads();
        v += n;
        lds[threadIdx.x] = v;
        __syncthreads();
    }
    int excl = v - t3;                // exclusive prefix of this thread
    cursor[base + 0] = excl;
    cursor[base + 1] = excl + t0;
    cursor[base + 2] = excl + t1;
    cursor[base + 3] = excl + t2;
    if (threadIdx.x == 255) chunkSums[blockIdx.x] = v;
}

__global__ __launch_bounds__(256) void scan_top_kernel(int* __restrict__ chunkSums)
{
    __shared__ int lds[256];
    int t = threadIdx.x;
    int x = chunkSums[t];
    lds[t] = x;
    __syncthreads();
    int v = x;
    for (int off = 1; off < 256; off <<= 1) {
        int n = (t >= off) ? lds[t - off] : 0;
        __syncthreads();
        v += n;
        lds[t] = v;
        __syncthreads();
    }
    chunkSums[t] = v - x;             // exclusive
}

__global__ __launch_bounds__(256) void scan_add_kernel(
    int* __restrict__ cursor, const int* __restrict__ chunkSums)
{
    int i = blockIdx.x * 256 + threadIdx.x;
    cursor[i] += chunkSums[i >> 10];
}

__global__ __launch_bounds__(256) void sort_kernel(
    const float* __restrict__ pts, int* __restrict__ cursor,
    int* __restrict__ sorted, int npts)
{
    int p = blockIdx.x * 256 + threadIdx.x;
    if (p >= npts) return;
    float px = pts[p * 3 + 0];
    float py = pts[p * 3 + 1];
    float pz = pts[p * 3 + 2];
    int bx = (int)floorf(px);
    int by = (int)floorf(py);
    int bz = (int)floorf(pz);
    bx = min(max(bx, 0), G - 1);
    by = min(max(by, 0), G - 1);
    bz = min(max(bz, 0), G - 1);
    int fl = (bx * G + by) * G + bz;
    int idx = atomicAdd(&cursor[fl], 1);
    sorted[idx] = p;
}

// ---------------------------------------------------------------------------
// Stage 4: trilinear devoxelize + residual linear.
// Block = 256 threads = 4 waves, 64 points/block, 16 points/WAVE.
// Lane = output channel. Per-wave persistent state:
//   - Wl column for lane c held in 32 VGPRs (loaded once)
//   - feats rows cooperatively staged into LDS (64 rows in flight ->
//     HBM latency amortized; read back as broadcast ds_read_b128)
// Convo corner gathers stay L1/L2-hot thanks to the voxel sort +
// XCD-bijective block swizzle.
// ---------------------------------------------------------------------------
#define PPB 64   // points per block
#define PPW 16   // points per wave

__global__ __launch_bounds__(256) void gather_kernel(
    const float* __restrict__ pts, const float* __restrict__ feats,
    const float* __restrict__ convo, const float* __restrict__ cnts,
    const float* __restrict__ Wl, const float* __restrict__ bl,
    const int* __restrict__ sorted,
    float* __restrict__ out, int npts)
{
    __shared__ float sF[PPB][INC];    // 8 KB staged feats rows (sorted order)
    __shared__ int   sP[PPB];         // original point ids
    __shared__ float sPts[PPB][3];    // coords

    int t = threadIdx.x;

    // XCD-bijective swizzle: XCD (= bid%8) owns a contiguous slice of the
    // sorted point range -> convo corner reuse stays inside one XCD's L2.
    int bid = blockIdx.x;
    int nwg = gridDim.x;
    int q = nwg >> 3, r = nwg & 7;
    int xcd = bid & 7, local = bid >> 3;
    int swz = (xcd < r) ? (xcd * (q + 1) + local)
                        : (r * (q + 1) + (xcd - r) * q + local);
    int nbase = swz * PPB;

    // ---- stage sorted ids
    if (t < PPB) {
        int slot = nbase + t;
        sP[t] = (slot < npts) ? sorted[slot] : 0;
    }
    __syncthreads();

    // ---- stage coords + feats rows (coalesced: 8 threads per 128B row)
    if (t < 192) {
        int rr = t & 63, comp = t >> 6;
        sPts[rr][comp] = pts[(size_t)sP[rr] * 3 + comp];
    }
#pragma unroll
    for (int i = t; i < PPB * INC / 4; i += 256) {
        int rr = i >> 3, part = i & 7;
        ((float4*)sF[rr])[part] =
            ((const float4*)(feats + (size_t)sP[rr] * INC))[part];
    }
    __syncthreads();

    // ---- per-lane persistent Wl column + bias (Wl layout [c][k], 128B rows)
    int wv = t >> 6;
    int c  = t & 63;
    float4 Wreg[8];
    const float4* wrow = (const float4*)(Wl + (size_t)c * INC);
#pragma unroll
    for (int j = 0; j < 8; j++) Wreg[j] = wrow[j];
    float bias = bl[c];

    int pbeg = wv * PPW;
#pragma unroll 1
    for (int i = 0; i < PPW; i++) {
        int li = pbeg + i;
        int slot = nbase + li;
        int p = sP[li];
        float px = sPts[li][0];
        float py = sPts[li][1];
        float pz = sPts[li][2];
        int bx = (int)floorf(px);
        int by = (int)floorf(py);
        int bz = (int)floorf(pz);
        float fx = px - (float)bx;
        float fy = py - (float)by;
        float fz = pz - (float)bz;

        // ---- issue all 8 corner gathers early (independent, overlap VALU)
        float cw[8];
        float cv[8];
#pragma unroll
        for (int corner = 0; corner < 8; corner++) {
            int dx = (corner >> 2) & 1;
            int dy = (corner >> 1) & 1;
            int dz = corner & 1;
            int nx = bx + dx, ny = by + dy, nz = bz + dz;
            bool inb = ((unsigned)nx < (unsigned)G) && ((unsigned)ny < (unsigned)G) &&
                       ((unsigned)nz < (unsigned)G);
            int cx = min(max(nx, 0), G - 1);
            int cy = min(max(ny, 0), G - 1);
            int cz = min(max(nz, 0), G - 1);
            int fl = (cx * G + cy) * G + cz;
            float w = (dx ? fx : 1.0f - fx) * (dy ? fy : 1.0f - fy) * (dz ? fz : 1.0f - fz);
            if (!inb || !(cnts[fl] > 0.0f)) w = 0.0f;
            cw[corner] = w;
            cv[corner] = convo[(size_t)fl * OUTC + c];
        }

        float acc = bias;

        // ---- residual linear: broadcast ds_read_b128 of staged feats row,
        //      FMA against the register-resident Wl column
        const float4* f4 = (const float4*)sF[li];
#pragma unroll
        for (int j = 0; j < 8; j++) {
            float4 f = f4[j];
            acc += f.x * Wreg[j].x;
            acc += f.y * Wreg[j].y;
            acc += f.z * Wreg[j].z;
            acc += f.w * Wreg[j].w;
        }

#pragma unroll
        for (int corner = 0; corner < 8; corner++)
            acc += cw[corner] * cv[corner];

        if (slot < npts)
            out[(size_t)p * OUTC + c] = acc;
    }
}

// ---------------------------------------------------------------------------
extern "C" void kernel_launch(void* const* d_in, const int* in_sizes, int n_in,
                              void* d_out, int out_size, void* d_ws, size_t ws_size,
                              hipStream_t stream)
{
    const float* pts   = (const float*)d_in[0];
    const float* feats = (const float*)d_in[1];
    const float* Wc    = (const float*)d_in[2];
    const float* Wl    = (const float*)d_in[3];
    const float* bl    = (const float*)d_in[4];
    float* out = (float*)d_out;
    int npts = in_sizes[0] / 3;

    // workspace layout
    float* sums  = (float*)d_ws;                    // NVOX*32
    float* cnts  = sums + (size_t)NVOX * INC;       // NVOX
    float* convo = cnts + NVOX;                     // NVOX*64

    // sort scratch ALIASES the sums region -- only touched after conv_kernel
    // has fully consumed sums (stream-ordered).
    int* cursor    = (int*)sums;                    // NVOX
    int* chunkSums = cursor + NVOX;                 // NCHUNK (=256)
    int* sorted    = chunkSums + NCHUNK;            // npts

    // zero scatter accumulators (sums + cnts = NVOX*33 floats)
    hipMemsetAsync(d_ws, 0, (size_t)NVOX * (INC + 1) * sizeof(float), stream);

    int scatter_blocks = (npts * 8 + 255) / 256;
    scatter_kernel<<<scatter_blocks, 256, 0, stream>>>(pts, feats, sums, cnts, npts);

    normalize_kernel<<<(NVOX * 8) / 256, 256, 0, stream>>>(sums, cnts);

    conv_kernel<<<NVOX / 256, 256, 0, stream>>>(sums, Wc, convo);

    // counting sort of points by voxel (scratch aliases sums; runs after conv)
    scan_local_kernel<<<NCHUNK, 256, 0, stream>>>(cnts, cursor, chunkSums);
    scan_top_kernel<<<1, 256, 0, stream>>>(chunkSums);
    scan_add_kernel<<<NVOX / 256, 256, 0, stream>>>(cursor, chunkSums);
    sort_kernel<<<(npts + 255) / 256, 256, 0, stream>>>(pts, cursor, sorted, npts);

    int gather_blocks = (npts + PPB - 1) / PPB;
    gather_kernel<<<gather_blocks, 256, 0, stream>>>(pts, feats, convo, cnts,
                                                     Wl, bl, sorted, out, npts);
}

// Round 3
// 1488.954 us; speedup vs baseline: 1.4442x; 1.1538x over previous
//
#include <hip/hip_runtime.h>
#include <hip/hip_bf16.h>

#define G 64
#define NVOX (G*G*G)
#define INC 32
#define OUTC 64
#define NCHUNK (NVOX/1024)   // 256 chunks for the two-level scan

// ---------------------------------------------------------------------------
// Stage 1: scatter-mean accumulation. 8 threads per point, 4 channels each.
// ---------------------------------------------------------------------------
__global__ __launch_bounds__(256) void scatter_kernel(
    const float* __restrict__ pts, const float* __restrict__ feats,
    float* __restrict__ sums, float* __restrict__ cnts, int npts)
{
    int tid = blockIdx.x * 256 + threadIdx.x;
    int p = tid >> 3;
    int q = tid & 7;
    if (p >= npts) return;

    float px = pts[p * 3 + 0];
    float py = pts[p * 3 + 1];
    float pz = pts[p * 3 + 2];
    int bx = (int)floorf(px);
    int by = (int)floorf(py);
    int bz = (int)floorf(pz);
    bx = min(max(bx, 0), G - 1);
    by = min(max(by, 0), G - 1);
    bz = min(max(bz, 0), G - 1);
    int fl = (bx * G + by) * G + bz;

    float4 f = ((const float4*)feats)[p * 8 + q];
    float* dst = sums + (size_t)fl * INC + q * 4;
    atomicAdd(dst + 0, f.x);
    atomicAdd(dst + 1, f.y);
    atomicAdd(dst + 2, f.z);
    atomicAdd(dst + 3, f.w);
    if (q == 0) atomicAdd(cnts + fl, 1.0f);
}

// ---------------------------------------------------------------------------
// Stage 2: sums -> means (in place). One thread per float4 (8 per voxel).
// ---------------------------------------------------------------------------
__global__ __launch_bounds__(256) void normalize_kernel(
    float* __restrict__ sums, const float* __restrict__ cnts)
{
    int t = blockIdx.x * 256 + threadIdx.x;   // over NVOX*8 float4s
    int v = t >> 3;
    float c = cnts[v];
    float inv = 1.0f / fmaxf(c, 1.0f);
    float4* s4 = (float4*)sums;
    float4 a = s4[t];
    a.x *= inv; a.y *= inv; a.z *= inv; a.w *= inv;
    s4[t] = a;
}

// ---------------------------------------------------------------------------
// Stage 3: dense 3x3x3 conv, 32 -> 64 channels, SAME padding.
// One thread per voxel, 64 fp32 accumulators; W reads are wave-uniform.
// ---------------------------------------------------------------------------
__global__ __launch_bounds__(256) void conv_kernel(
    const float* __restrict__ voxf, const float* __restrict__ Wc,
    float* __restrict__ convo)
{
    int v = blockIdx.x * 256 + threadIdx.x;
    int z = v & (G - 1);
    int y = (v >> 6) & (G - 1);
    int x = v >> 12;

    float acc[OUTC];
#pragma unroll
    for (int n = 0; n < OUTC; n++) acc[n] = 0.0f;

#pragma unroll 1
    for (int off = 0; off < 27; off++) {
        int dx = off / 9 - 1;
        int dy = (off / 3) % 3 - 1;
        int dz = off % 3 - 1;
        int nx = x + dx, ny = y + dy, nz = z + dz;
        if ((unsigned)nx >= (unsigned)G || (unsigned)ny >= (unsigned)G ||
            (unsigned)nz >= (unsigned)G)
            continue;
        int nb = v + dx * (G * G) + dy * G + dz;
        const float4* in4 = (const float4*)(voxf + (size_t)nb * INC);
        const float* Wo = Wc + off * (INC * OUTC);
#pragma unroll 1
        for (int k4 = 0; k4 < 8; k4++) {
            float4 f = in4[k4];
            const float* wr0 = Wo + (k4 * 4 + 0) * OUTC;
            const float* wr1 = Wo + (k4 * 4 + 1) * OUTC;
            const float* wr2 = Wo + (k4 * 4 + 2) * OUTC;
            const float* wr3 = Wo + (k4 * 4 + 3) * OUTC;
#pragma unroll
            for (int n = 0; n < OUTC; n++) {
                acc[n] += f.x * wr0[n];
                acc[n] += f.y * wr1[n];
                acc[n] += f.z * wr2[n];
                acc[n] += f.w * wr3[n];
            }
        }
    }

    float4* o4 = (float4*)(convo + (size_t)v * OUTC);
#pragma unroll
    for (int n = 0; n < OUTC / 4; n++)
        o4[n] = make_float4(acc[4 * n], acc[4 * n + 1], acc[4 * n + 2], acc[4 * n + 3]);
}

// ---------------------------------------------------------------------------
// Counting sort of points by voxel id (for gather cache locality).
// ---------------------------------------------------------------------------
__global__ __launch_bounds__(256) void scan_local_kernel(
    const float* __restrict__ cnts, int* __restrict__ cursor,
    int* __restrict__ chunkSums)
{
    __shared__ int lds[256];
    int base = blockIdx.x * 1024 + threadIdx.x * 4;
    int e0 = (int)cnts[base + 0];
    int e1 = (int)cnts[base + 1];
    int e2 = (int)cnts[base + 2];
    int e3 = (int)cnts[base + 3];
    int t0 = e0;
    int t1 = t0 + e1;
    int t2 = t1 + e2;
    int t3 = t2 + e3;                 // thread total
    lds[threadIdx.x] = t3;
    __syncthreads();
    int v = t3;
    for (int off = 1; off < 256; off <<= 1) {
        int n = (threadIdx.x >= off) ? lds[threadIdx.x - off] : 0;
        __syncthreads();
        v += n;
        lds[threadIdx.x] = v;
        __syncthreads();
    }
    int excl = v - t3;                // exclusive prefix of this thread
    cursor[base + 0] = excl;
    cursor[base + 1] = excl + t0;
    cursor[base + 2] = excl + t1;
    cursor[base + 3] = excl + t2;
    if (threadIdx.x == 255) chunkSums[blockIdx.x] = v;
}

__global__ __launch_bounds__(256) void scan_top_kernel(int* __restrict__ chunkSums)
{
    __shared__ int lds[256];
    int t = threadIdx.x;
    int x = chunkSums[t];
    lds[t] = x;
    __syncthreads();
    int v = x;
    for (int off = 1; off < 256; off <<= 1) {
        int n = (t >= off) ? lds[t - off] : 0;
        __syncthreads();
        v += n;
        lds[t] = v;
        __syncthreads();
    }
    chunkSums[t] = v - x;             // exclusive
}

__global__ __launch_bounds__(256) void scan_add_kernel(
    int* __restrict__ cursor, const int* __restrict__ chunkSums)
{
    int i = blockIdx.x * 256 + threadIdx.x;
    cursor[i] += chunkSums[i >> 10];
}

__global__ __launch_bounds__(256) void sort_kernel(
    const float* __restrict__ pts, int* __restrict__ cursor,
    int* __restrict__ sorted, int npts)
{
    int p = blockIdx.x * 256 + threadIdx.x;
    if (p >= npts) return;
    float px = pts[p * 3 + 0];
    float py = pts[p * 3 + 1];
    float pz = pts[p * 3 + 2];
    int bx = (int)floorf(px);
    int by = (int)floorf(py);
    int bz = (int)floorf(pz);
    bx = min(max(bx, 0), G - 1);
    by = min(max(by, 0), G - 1);
    bz = min(max(bz, 0), G - 1);
    int fl = (bx * G + by) * G + bz;
    int idx = atomicAdd(&cursor[fl], 1);
    sorted[idx] = p;
}

// ---------------------------------------------------------------------------
// Stage 4: trilinear devoxelize + residual linear.
// Block = 256 threads = 4 waves, 64 points/block, 16 points/WAVE.
// Lane = output channel; the point index is WAVE-UNIFORM.
// Key exploit: points are voxel-sorted, so consecutive points usually share
// the base voxel -> the 8 corner values (with occupancy mask folded in) and
// the 4 z-deltas are reused across the run via a wave-uniform branch.
// Per point: separable trilinear (10 VALU) + 32-FMA residual linear.
// ---------------------------------------------------------------------------
#define PPB 64   // points per block
#define PPW 16   // points per wave

__global__ __launch_bounds__(256) void gather_kernel(
    const float* __restrict__ pts, const float* __restrict__ feats,
    const float* __restrict__ convo, const float* __restrict__ cnts,
    const float* __restrict__ Wl, const float* __restrict__ bl,
    const int* __restrict__ sorted,
    float* __restrict__ out, int npts)
{
    __shared__ float sF[PPB][INC];    // 8 KB staged feats rows (sorted order)
    __shared__ int   sP[PPB];         // original point ids
    __shared__ float sPts[PPB][3];    // coords

    int t = threadIdx.x;

    // XCD-bijective swizzle: XCD (= bid%8) owns a contiguous slice of the
    // sorted point range -> convo corner reuse stays inside one XCD's L2.
    int bid = blockIdx.x;
    int nwg = gridDim.x;
    int q = nwg >> 3, r = nwg & 7;
    int xcd = bid & 7, local = bid >> 3;
    int swz = (xcd < r) ? (xcd * (q + 1) + local)
                        : (r * (q + 1) + (xcd - r) * q + local);
    int nbase = swz * PPB;

    // ---- stage sorted ids
    if (t < PPB) {
        int slot = nbase + t;
        sP[t] = (slot < npts) ? sorted[slot] : 0;
    }
    __syncthreads();

    // ---- stage coords + feats rows (coalesced: 8 threads per 128B row)
    if (t < 192) {
        int rr = t & 63, comp = t >> 6;
        sPts[rr][comp] = pts[(size_t)sP[rr] * 3 + comp];
    }
#pragma unroll
    for (int i = t; i < PPB * INC / 4; i += 256) {
        int rr = i >> 3, part = i & 7;
        ((float4*)sF[rr])[part] =
            ((const float4*)(feats + (size_t)sP[rr] * INC))[part];
    }
    __syncthreads();

    // ---- per-lane persistent Wl column + bias (Wl layout [c][k], 128B rows)
    int wv = t >> 6;
    int c  = t & 63;
    float4 Wreg[8];
    const float4* wrow = (const float4*)(Wl + (size_t)c * INC);
#pragma unroll
    for (int j = 0; j < 8; j++) Wreg[j] = wrow[j];
    float bias = bl[c];

    int pbeg = wv * PPW;

    // per-voxel cached state (valid while base voxel unchanged)
    int prev_fl = -1;
    float cvm[8];   // corner values with (inb && occ) mask folded in
    float dzd[4];   // z-direction deltas, precomputed per voxel

#pragma unroll 1
    for (int i = 0; i < PPW; i++) {
        int li = pbeg + i;
        int slot = nbase + li;
        int p = sP[li];
        float px = sPts[li][0];
        float py = sPts[li][1];
        float pz = sPts[li][2];
        int bx = (int)floorf(px);
        int by = (int)floorf(py);
        int bz = (int)floorf(pz);
        int flb = (bx * G + by) * G + bz;

        if (flb != prev_fl) {          // wave-uniform branch (point is uniform)
            prev_fl = flb;
#pragma unroll
            for (int corner = 0; corner < 8; corner++) {
                int dx = (corner >> 2) & 1;
                int dy = (corner >> 1) & 1;
                int dz = corner & 1;
                int nx = bx + dx, ny = by + dy, nz = bz + dz;
                bool inb = ((unsigned)nx < (unsigned)G) &&
                           ((unsigned)ny < (unsigned)G) &&
                           ((unsigned)nz < (unsigned)G);
                int cx = min(nx, G - 1);
                int cy = min(ny, G - 1);
                int cz = min(nz, G - 1);
                int fl = (cx * G + cy) * G + cz;
                bool ok = inb && (cnts[fl] > 0.0f);
                float v = convo[(size_t)fl * OUTC + c];
                cvm[corner] = ok ? v : 0.0f;
            }
            dzd[0] = cvm[1] - cvm[0];
            dzd[1] = cvm[3] - cvm[2];
            dzd[2] = cvm[5] - cvm[4];
            dzd[3] = cvm[7] - cvm[6];
        }

        float fx = px - (float)bx;
        float fy = py - (float)by;
        float fz = pz - (float)bz;

        // separable trilinear: z lerps (deltas precomputed), then y, then x
        float c00 = fmaf(fz, dzd[0], cvm[0]);
        float c01 = fmaf(fz, dzd[1], cvm[2]);
        float c10 = fmaf(fz, dzd[2], cvm[4]);
        float c11 = fmaf(fz, dzd[3], cvm[6]);
        float c0  = fmaf(fy, c01 - c00, c00);
        float c1  = fmaf(fy, c11 - c10, c10);
        float tri = fmaf(fx, c1 - c0, c0);

        float acc = bias + tri;

        // residual linear: broadcast ds_read_b128 of staged feats row,
        // FMA against the register-resident Wl column
        const float4* f4 = (const float4*)sF[li];
#pragma unroll
        for (int j = 0; j < 8; j++) {
            float4 f = f4[j];
            acc += f.x * Wreg[j].x;
            acc += f.y * Wreg[j].y;
            acc += f.z * Wreg[j].z;
            acc += f.w * Wreg[j].w;
        }

        if (slot < npts)
            out[(size_t)p * OUTC + c] = acc;
    }
}

// ---------------------------------------------------------------------------
extern "C" void kernel_launch(void* const* d_in, const int* in_sizes, int n_in,
                              void* d_out, int out_size, void* d_ws, size_t ws_size,
                              hipStream_t stream)
{
    const float* pts   = (const float*)d_in[0];
    const float* feats = (const float*)d_in[1];
    const float* Wc    = (const float*)d_in[2];
    const float* Wl    = (const float*)d_in[3];
    const float* bl    = (const float*)d_in[4];
    float* out = (float*)d_out;
    int npts = in_sizes[0] / 3;

    // workspace layout
    float* sums  = (float*)d_ws;                    // NVOX*32
    float* cnts  = sums + (size_t)NVOX * INC;       // NVOX
    float* convo = cnts + NVOX;                     // NVOX*64

    // sort scratch ALIASES the sums region -- only touched after conv_kernel
    // has fully consumed sums (stream-ordered).
    int* cursor    = (int*)sums;                    // NVOX
    int* chunkSums = cursor + NVOX;                 // NCHUNK (=256)
    int* sorted    = chunkSums + NCHUNK;            // npts

    // zero scatter accumulators (sums + cnts = NVOX*33 floats)
    hipMemsetAsync(d_ws, 0, (size_t)NVOX * (INC + 1) * sizeof(float), stream);

    int scatter_blocks = (npts * 8 + 255) / 256;
    scatter_kernel<<<scatter_blocks, 256, 0, stream>>>(pts, feats, sums, cnts, npts);

    normalize_kernel<<<(NVOX * 8) / 256, 256, 0, stream>>>(sums, cnts);

    conv_kernel<<<NVOX / 256, 256, 0, stream>>>(sums, Wc, convo);

    // counting sort of points by voxel (scratch aliases sums; runs after conv)
    scan_local_kernel<<<NCHUNK, 256, 0, stream>>>(cnts, cursor, chunkSums);
    scan_top_kernel<<<1, 256, 0, stream>>>(chunkSums);
    scan_add_kernel<<<NVOX / 256, 256, 0, stream>>>(cursor, chunkSums);
    sort_kernel<<<(npts + 255) / 256, 256, 0, stream>>>(pts, cursor, sorted, npts);

    int gather_blocks = (npts + PPB - 1) / PPB;
    gather_kernel<<<gather_blocks, 256, 0, stream>>>(pts, feats, convo, cnts,
                                                     Wl, bl, sorted, out, npts);
}

// Round 4
// 1118.930 us; speedup vs baseline: 1.9218x; 1.3307x over previous
//
#include <hip/hip_runtime.h>
#include <hip/hip_bf16.h>

#define G 64
#define NVOX (G*G*G)
#define INC 32
#define OUTC 64
#define NCHUNK (NVOX/1024)   // 256 chunks for the two-level scan

// ---------------------------------------------------------------------------
// Stage 1: per-voxel point count. One int atomic per point (replaces the old
// 33M-float-atomic scatter; the mean is computed post-sort with no atomics).
// ---------------------------------------------------------------------------
__global__ __launch_bounds__(256) void count_kernel(
    const float* __restrict__ pts, int* __restrict__ cnts, int npts)
{
    int p = blockIdx.x * 256 + threadIdx.x;
    if (p >= npts) return;
    float px = pts[p * 3 + 0];
    float py = pts[p * 3 + 1];
    float pz = pts[p * 3 + 2];
    int bx = (int)floorf(px);
    int by = (int)floorf(py);
    int bz = (int)floorf(pz);
    bx = min(max(bx, 0), G - 1);
    by = min(max(by, 0), G - 1);
    bz = min(max(bz, 0), G - 1);
    int fl = (bx * G + by) * G + bz;
    atomicAdd(&cnts[fl], 1);
}

// ---------------------------------------------------------------------------
// Counting sort of points by voxel id.
// scan_local: per-1024-element chunk exclusive scan of cnts -> cursor.
// ---------------------------------------------------------------------------
__global__ __launch_bounds__(256) void scan_local_kernel(
    const int* __restrict__ cnts, int* __restrict__ cursor,
    int* __restrict__ chunkSums)
{
    __shared__ int lds[256];
    int base = blockIdx.x * 1024 + threadIdx.x * 4;
    int e0 = cnts[base + 0];
    int e1 = cnts[base + 1];
    int e2 = cnts[base + 2];
    int e3 = cnts[base + 3];
    int t0 = e0;
    int t1 = t0 + e1;
    int t2 = t1 + e2;
    int t3 = t2 + e3;                 // thread total
    lds[threadIdx.x] = t3;
    __syncthreads();
    int v = t3;
    for (int off = 1; off < 256; off <<= 1) {
        int n = (threadIdx.x >= off) ? lds[threadIdx.x - off] : 0;
        __syncthreads();
        v += n;
        lds[threadIdx.x] = v;
        __syncthreads();
    }
    int excl = v - t3;                // exclusive prefix of this thread
    cursor[base + 0] = excl;
    cursor[base + 1] = excl + t0;
    cursor[base + 2] = excl + t1;
    cursor[base + 3] = excl + t2;
    if (threadIdx.x == 255) chunkSums[blockIdx.x] = v;
}

__global__ __launch_bounds__(256) void scan_top_kernel(int* __restrict__ chunkSums)
{
    __shared__ int lds[256];
    int t = threadIdx.x;
    int x = chunkSums[t];
    lds[t] = x;
    __syncthreads();
    int v = x;
    for (int off = 1; off < 256; off <<= 1) {
        int n = (t >= off) ? lds[t - off] : 0;
        __syncthreads();
        v += n;
        lds[t] = v;
        __syncthreads();
    }
    chunkSums[t] = v - x;             // exclusive
}

__global__ __launch_bounds__(256) void scan_add_kernel(
    int* __restrict__ cursor, const int* __restrict__ chunkSums)
{
    int i = blockIdx.x * 256 + threadIdx.x;
    cursor[i] += chunkSums[i >> 10];
}

__global__ __launch_bounds__(256) void sort_kernel(
    const float* __restrict__ pts, int* __restrict__ cursor,
    int* __restrict__ sorted, int npts)
{
    int p = blockIdx.x * 256 + threadIdx.x;
    if (p >= npts) return;
    float px = pts[p * 3 + 0];
    float py = pts[p * 3 + 1];
    float pz = pts[p * 3 + 2];
    int bx = (int)floorf(px);
    int by = (int)floorf(py);
    int bz = (int)floorf(pz);
    bx = min(max(bx, 0), G - 1);
    by = min(max(by, 0), G - 1);
    bz = min(max(bz, 0), G - 1);
    int fl = (bx * G + by) * G + bz;
    int idx = atomicAdd(&cursor[fl], 1);
    sorted[idx] = p;
}

// ---------------------------------------------------------------------------
// Stage 2: segmented mean. 8 threads per voxel walk the voxel's sorted
// segment (coalesced 128B feats rows), then write the mean once.
// Zero atomics; empty voxels write zeros (so no memset of sums needed).
// After sort, cursor[v] = segment END; start = end - cnts[v].
// ---------------------------------------------------------------------------
__global__ __launch_bounds__(256) void voxelize_kernel(
    const int* __restrict__ cnts, const int* __restrict__ cursorEnd,
    const int* __restrict__ sorted, const float* __restrict__ feats,
    float* __restrict__ sums)
{
    int tid = blockIdx.x * 256 + threadIdx.x;   // NVOX*8 threads
    int v = tid >> 3;
    int q = tid & 7;
    int cnt = cnts[v];
    int end = cursorEnd[v];
    int beg = end - cnt;
    float4 acc = make_float4(0.f, 0.f, 0.f, 0.f);
    for (int s = beg; s < end; s++) {
        int p = sorted[s];
        float4 f = ((const float4*)(feats + (size_t)p * INC))[q];
        acc.x += f.x; acc.y += f.y; acc.z += f.z; acc.w += f.w;
    }
    float inv = 1.0f / fmaxf((float)cnt, 1.0f);
    acc.x *= inv; acc.y *= inv; acc.z *= inv; acc.w *= inv;
    ((float4*)(sums + (size_t)v * INC))[q] = acc;
}

// ---------------------------------------------------------------------------
// Stage 3: dense 3x3x3 conv, 32 -> 64 channels, SAME padding.
// One thread per voxel, 64 fp32 accumulators; W reads are wave-uniform.
// ---------------------------------------------------------------------------
__global__ __launch_bounds__(256) void conv_kernel(
    const float* __restrict__ voxf, const float* __restrict__ Wc,
    float* __restrict__ convo)
{
    int v = blockIdx.x * 256 + threadIdx.x;
    int z = v & (G - 1);
    int y = (v >> 6) & (G - 1);
    int x = v >> 12;

    float acc[OUTC];
#pragma unroll
    for (int n = 0; n < OUTC; n++) acc[n] = 0.0f;

#pragma unroll 1
    for (int off = 0; off < 27; off++) {
        int dx = off / 9 - 1;
        int dy = (off / 3) % 3 - 1;
        int dz = off % 3 - 1;
        int nx = x + dx, ny = y + dy, nz = z + dz;
        if ((unsigned)nx >= (unsigned)G || (unsigned)ny >= (unsigned)G ||
            (unsigned)nz >= (unsigned)G)
            continue;
        int nb = v + dx * (G * G) + dy * G + dz;
        const float4* in4 = (const float4*)(voxf + (size_t)nb * INC);
        const float* Wo = Wc + off * (INC * OUTC);
#pragma unroll 1
        for (int k4 = 0; k4 < 8; k4++) {
            float4 f = in4[k4];
            const float* wr0 = Wo + (k4 * 4 + 0) * OUTC;
            const float* wr1 = Wo + (k4 * 4 + 1) * OUTC;
            const float* wr2 = Wo + (k4 * 4 + 2) * OUTC;
            const float* wr3 = Wo + (k4 * 4 + 3) * OUTC;
#pragma unroll
            for (int n = 0; n < OUTC; n++) {
                acc[n] += f.x * wr0[n];
                acc[n] += f.y * wr1[n];
                acc[n] += f.z * wr2[n];
                acc[n] += f.w * wr3[n];
            }
        }
    }

    float4* o4 = (float4*)(convo + (size_t)v * OUTC);
#pragma unroll
    for (int n = 0; n < OUTC / 4; n++)
        o4[n] = make_float4(acc[4 * n], acc[4 * n + 1], acc[4 * n + 2], acc[4 * n + 3]);
}

// ---------------------------------------------------------------------------
// Stage 4: trilinear devoxelize + residual linear.
// Block = 256 threads = 4 waves, 64 points/block, 16 points/WAVE.
// Lane = output channel; the point index is WAVE-UNIFORM.
// Voxel-sorted points -> corner values (occupancy mask folded in) and
// z-deltas cached across the run via a wave-uniform branch.
// ---------------------------------------------------------------------------
#define PPB 64   // points per block
#define PPW 16   // points per wave

__global__ __launch_bounds__(256) void gather_kernel(
    const float* __restrict__ pts, const float* __restrict__ feats,
    const float* __restrict__ convo, const int* __restrict__ cnts,
    const float* __restrict__ Wl, const float* __restrict__ bl,
    const int* __restrict__ sorted,
    float* __restrict__ out, int npts)
{
    __shared__ float sF[PPB][INC];    // 8 KB staged feats rows (sorted order)
    __shared__ int   sP[PPB];         // original point ids
    __shared__ float sPts[PPB][3];    // coords

    int t = threadIdx.x;

    // XCD-bijective swizzle: XCD (= bid%8) owns a contiguous slice of the
    // sorted point range -> convo corner reuse stays inside one XCD's L2.
    int bid = blockIdx.x;
    int nwg = gridDim.x;
    int q = nwg >> 3, r = nwg & 7;
    int xcd = bid & 7, local = bid >> 3;
    int swz = (xcd < r) ? (xcd * (q + 1) + local)
                        : (r * (q + 1) + (xcd - r) * q + local);
    int nbase = swz * PPB;

    // ---- stage sorted ids
    if (t < PPB) {
        int slot = nbase + t;
        sP[t] = (slot < npts) ? sorted[slot] : 0;
    }
    __syncthreads();

    // ---- stage coords + feats rows (coalesced: 8 threads per 128B row)
    if (t < 192) {
        int rr = t & 63, comp = t >> 6;
        sPts[rr][comp] = pts[(size_t)sP[rr] * 3 + comp];
    }
#pragma unroll
    for (int i = t; i < PPB * INC / 4; i += 256) {
        int rr = i >> 3, part = i & 7;
        ((float4*)sF[rr])[part] =
            ((const float4*)(feats + (size_t)sP[rr] * INC))[part];
    }
    __syncthreads();

    // ---- per-lane persistent Wl column + bias (Wl layout [c][k], 128B rows)
    int wv = t >> 6;
    int c  = t & 63;
    float4 Wreg[8];
    const float4* wrow = (const float4*)(Wl + (size_t)c * INC);
#pragma unroll
    for (int j = 0; j < 8; j++) Wreg[j] = wrow[j];
    float bias = bl[c];

    int pbeg = wv * PPW;

    // per-voxel cached state (valid while base voxel unchanged)
    int prev_fl = -1;
    float cvm[8];   // corner values with (inb && occ) mask folded in
    float dzd[4];   // z-direction deltas, precomputed per voxel

#pragma unroll 1
    for (int i = 0; i < PPW; i++) {
        int li = pbeg + i;
        int slot = nbase + li;
        int p = sP[li];
        float px = sPts[li][0];
        float py = sPts[li][1];
        float pz = sPts[li][2];
        int bx = (int)floorf(px);
        int by = (int)floorf(py);
        int bz = (int)floorf(pz);
        int flb = (bx * G + by) * G + bz;

        if (flb != prev_fl) {          // wave-uniform branch (point is uniform)
            prev_fl = flb;
#pragma unroll
            for (int corner = 0; corner < 8; corner++) {
                int dx = (corner >> 2) & 1;
                int dy = (corner >> 1) & 1;
                int dz = corner & 1;
                int nx = bx + dx, ny = by + dy, nz = bz + dz;
                bool inb = ((unsigned)nx < (unsigned)G) &&
                           ((unsigned)ny < (unsigned)G) &&
                           ((unsigned)nz < (unsigned)G);
                int cx = min(nx, G - 1);
                int cy = min(ny, G - 1);
                int cz = min(nz, G - 1);
                int fl = (cx * G + cy) * G + cz;
                bool ok = inb && (cnts[fl] != 0);
                float v = convo[(size_t)fl * OUTC + c];
                cvm[corner] = ok ? v : 0.0f;
            }
            dzd[0] = cvm[1] - cvm[0];
            dzd[1] = cvm[3] - cvm[2];
            dzd[2] = cvm[5] - cvm[4];
            dzd[3] = cvm[7] - cvm[6];
        }

        float fx = px - (float)bx;
        float fy = py - (float)by;
        float fz = pz - (float)bz;

        // separable trilinear: z lerps (deltas precomputed), then y, then x
        float c00 = fmaf(fz, dzd[0], cvm[0]);
        float c01 = fmaf(fz, dzd[1], cvm[2]);
        float c10 = fmaf(fz, dzd[2], cvm[4]);
        float c11 = fmaf(fz, dzd[3], cvm[6]);
        float c0  = fmaf(fy, c01 - c00, c00);
        float c1  = fmaf(fy, c11 - c10, c10);
        float tri = fmaf(fx, c1 - c0, c0);

        float acc = bias + tri;

        // residual linear: broadcast ds_read_b128 of staged feats row,
        // FMA against the register-resident Wl column
        const float4* f4 = (const float4*)sF[li];
#pragma unroll
        for (int j = 0; j < 8; j++) {
            float4 f = f4[j];
            acc += f.x * Wreg[j].x;
            acc += f.y * Wreg[j].y;
            acc += f.z * Wreg[j].z;
            acc += f.w * Wreg[j].w;
        }

        if (slot < npts)
            out[(size_t)p * OUTC + c] = acc;
    }
}

// ---------------------------------------------------------------------------
extern "C" void kernel_launch(void* const* d_in, const int* in_sizes, int n_in,
                              void* d_out, int out_size, void* d_ws, size_t ws_size,
                              hipStream_t stream)
{
    const float* pts   = (const float*)d_in[0];
    const float* feats = (const float*)d_in[1];
    const float* Wc    = (const float*)d_in[2];
    const float* Wl    = (const float*)d_in[3];
    const float* bl    = (const float*)d_in[4];
    float* out = (float*)d_out;
    int npts = in_sizes[0] / 3;
    int npts_pad = (npts + 3) & ~3;                 // keep 16B alignment below

    // workspace layout (~106 MB):
    //   cnts   : NVOX ints
    //   sorted : npts_pad ints          (persists to gather)
    //   sums   : NVOX*32 floats         (voxel means; dead after conv)
    //   convo  : NVOX*64 floats
    //   cursor/chunkSums alias convo (dead until conv runs)
    int*   cnts   = (int*)d_ws;
    int*   sorted = cnts + NVOX;
    float* sums   = (float*)(sorted + npts_pad);
    float* convo  = sums + (size_t)NVOX * INC;
    int*   cursor    = (int*)convo;                 // NVOX (dies before conv)
    int*   chunkSums = cursor + NVOX;               // NCHUNK

    // zero only the counts (1 MB); sums needs no memset (voxelize writes all)
    hipMemsetAsync(cnts, 0, (size_t)NVOX * sizeof(int), stream);

    int pblocks = (npts + 255) / 256;
    count_kernel<<<pblocks, 256, 0, stream>>>(pts, cnts, npts);

    scan_local_kernel<<<NCHUNK, 256, 0, stream>>>(cnts, cursor, chunkSums);
    scan_top_kernel<<<1, 256, 0, stream>>>(chunkSums);
    scan_add_kernel<<<NVOX / 256, 256, 0, stream>>>(cursor, chunkSums);
    sort_kernel<<<pblocks, 256, 0, stream>>>(pts, cursor, sorted, npts);

    voxelize_kernel<<<(NVOX * 8) / 256, 256, 0, stream>>>(cnts, cursor, sorted,
                                                          feats, sums);

    conv_kernel<<<NVOX / 256, 256, 0, stream>>>(sums, Wc, convo);

    int gather_blocks = (npts + PPB - 1) / PPB;
    gather_kernel<<<gather_blocks, 256, 0, stream>>>(pts, feats, convo, cnts,
                                                     Wl, bl, sorted, out, npts);
}

// Round 5
// 812.778 us; speedup vs baseline: 2.6457x; 1.3767x over previous
//
#include <hip/hip_runtime.h>
#include <hip/hip_bf16.h>

#define G 64
#define NVOX (G*G*G)
#define INC 32
#define OUTC 64
#define NCHUNK (NVOX/1024)   // 256 chunks for the two-level scan

typedef __attribute__((ext_vector_type(8))) short short8;   // 8 bf16 = 4 VGPR
typedef __attribute__((ext_vector_type(4))) float f32x4;

__device__ __forceinline__ ushort f2bf(float f) {
    unsigned u = __float_as_uint(f);
    u += 0x7FFF + ((u >> 16) & 1);          // round-to-nearest-even
    return (ushort)(u >> 16);
}

// ---------------------------------------------------------------------------
// Stage 1: per-voxel point count. One int atomic per point.
// ---------------------------------------------------------------------------
__global__ __launch_bounds__(256) void count_kernel(
    const float* __restrict__ pts, int* __restrict__ cnts, int npts)
{
    int p = blockIdx.x * 256 + threadIdx.x;
    if (p >= npts) return;
    float px = pts[p * 3 + 0];
    float py = pts[p * 3 + 1];
    float pz = pts[p * 3 + 2];
    int bx = (int)floorf(px);
    int by = (int)floorf(py);
    int bz = (int)floorf(pz);
    bx = min(max(bx, 0), G - 1);
    by = min(max(by, 0), G - 1);
    bz = min(max(bz, 0), G - 1);
    int fl = (bx * G + by) * G + bz;
    atomicAdd(&cnts[fl], 1);
}

// ---------------------------------------------------------------------------
// Counting sort of points by voxel id.
// ---------------------------------------------------------------------------
__global__ __launch_bounds__(256) void scan_local_kernel(
    const int* __restrict__ cnts, int* __restrict__ cursor,
    int* __restrict__ chunkSums)
{
    __shared__ int lds[256];
    int base = blockIdx.x * 1024 + threadIdx.x * 4;
    int e0 = cnts[base + 0];
    int e1 = cnts[base + 1];
    int e2 = cnts[base + 2];
    int e3 = cnts[base + 3];
    int t0 = e0;
    int t1 = t0 + e1;
    int t2 = t1 + e2;
    int t3 = t2 + e3;                 // thread total
    lds[threadIdx.x] = t3;
    __syncthreads();
    int v = t3;
    for (int off = 1; off < 256; off <<= 1) {
        int n = (threadIdx.x >= off) ? lds[threadIdx.x - off] : 0;
        __syncthreads();
        v += n;
        lds[threadIdx.x] = v;
        __syncthreads();
    }
    int excl = v - t3;                // exclusive prefix of this thread
    cursor[base + 0] = excl;
    cursor[base + 1] = excl + t0;
    cursor[base + 2] = excl + t1;
    cursor[base + 3] = excl + t2;
    if (threadIdx.x == 255) chunkSums[blockIdx.x] = v;
}

__global__ __launch_bounds__(256) void scan_top_kernel(int* __restrict__ chunkSums)
{
    __shared__ int lds[256];
    int t = threadIdx.x;
    int x = chunkSums[t];
    lds[t] = x;
    __syncthreads();
    int v = x;
    for (int off = 1; off < 256; off <<= 1) {
        int n = (t >= off) ? lds[t - off] : 0;
        __syncthreads();
        v += n;
        lds[t] = v;
        __syncthreads();
    }
    chunkSums[t] = v - x;             // exclusive
}

__global__ __launch_bounds__(256) void scan_add_kernel(
    int* __restrict__ cursor, const int* __restrict__ chunkSums)
{
    int i = blockIdx.x * 256 + threadIdx.x;
    cursor[i] += chunkSums[i >> 10];
}

__global__ __launch_bounds__(256) void sort_kernel(
    const float* __restrict__ pts, int* __restrict__ cursor,
    int* __restrict__ sorted, int npts)
{
    int p = blockIdx.x * 256 + threadIdx.x;
    if (p >= npts) return;
    float px = pts[p * 3 + 0];
    float py = pts[p * 3 + 1];
    float pz = pts[p * 3 + 2];
    int bx = (int)floorf(px);
    int by = (int)floorf(py);
    int bz = (int)floorf(pz);
    bx = min(max(bx, 0), G - 1);
    by = min(max(by, 0), G - 1);
    bz = min(max(bz, 0), G - 1);
    int fl = (bx * G + by) * G + bz;
    int idx = atomicAdd(&cursor[fl], 1);
    sorted[idx] = p;
}

// ---------------------------------------------------------------------------
// Stage 2: segmented mean -> BF16 voxel features (conv's only input).
// 8 threads per voxel walk the voxel's sorted segment; zero atomics.
// Empty voxels write zeros (no memset needed).
// ---------------------------------------------------------------------------
__global__ __launch_bounds__(256) void voxelize_kernel(
    const int* __restrict__ cnts, const int* __restrict__ cursorEnd,
    const int* __restrict__ sorted, const float* __restrict__ feats,
    ushort* __restrict__ voxb)
{
    int tid = blockIdx.x * 256 + threadIdx.x;   // NVOX*8 threads
    int v = tid >> 3;
    int q = tid & 7;
    int cnt = cnts[v];
    int end = cursorEnd[v];
    int beg = end - cnt;
    float4 acc = make_float4(0.f, 0.f, 0.f, 0.f);
    for (int s = beg; s < end; s++) {
        int p = sorted[s];
        float4 f = ((const float4*)(feats + (size_t)p * INC))[q];
        acc.x += f.x; acc.y += f.y; acc.z += f.z; acc.w += f.w;
    }
    float inv = 1.0f / fmaxf((float)cnt, 1.0f);
    ushort4 o;
    o.x = f2bf(acc.x * inv);
    o.y = f2bf(acc.y * inv);
    o.z = f2bf(acc.z * inv);
    o.w = f2bf(acc.w * inv);
    *(ushort4*)(voxb + (size_t)v * INC + q * 4) = o;
}

// ---------------------------------------------------------------------------
// W transpose + bf16: Wt[off][n][k] = bf16(Wc[off][k][n]). 27*64*32 elems.
// ---------------------------------------------------------------------------
__global__ __launch_bounds__(256) void wtprep_kernel(
    const float* __restrict__ Wc, ushort* __restrict__ Wt)
{
    int i = blockIdx.x * 256 + threadIdx.x;   // 55296
    int off = i >> 11;
    int rem = i & 2047;
    int n = rem >> 5;
    int k = rem & 31;
    Wt[i] = f2bf(Wc[off * 2048 + k * 64 + n]);
}

// ---------------------------------------------------------------------------
// Stage 3: conv as implicit GEMM on MFMA (bf16 in, fp32 accum).
// Block = one xy column (4096 blocks), 256 thr = 4 waves.
// LDS stages the 9 neighbor columns, z = -1..64 zero-padded halo, bf16,
// XOR-swizzled (kg ^= (zz>>1)&3) -> 2-way banks on ds_read_b128 (free).
// Wave w: z-half (w&1), n-half (w>>1). Per offset: 2 A ds_reads +
// 2 coalesced B loads (1KB/wave, L1/L2-hot Wt) + 4 mfma_f32_16x16x32_bf16.
// C/D layout (m89-verified): col = lane&15, row = (lane>>4)*4 + reg.
// ---------------------------------------------------------------------------
__global__ __launch_bounds__(256) void conv_mfma_kernel(
    const ushort* __restrict__ voxb, const ushort* __restrict__ Wt,
    float* __restrict__ convo)
{
    __shared__ ushort sIn[9 * 66 * 32];   // 38,016 B

    // XCD-bijective swizzle (4096 % 8 == 0): adjacent columns share halo
    // data -> keep them on the same XCD's L2.
    int bid = blockIdx.x;
    int swz = (bid & 7) * 512 + (bid >> 3);
    int X = swz >> 6, Y = swz & 63;

    int t = threadIdx.x;

    // ---- stage 9 columns x 66 z-slots x 32 ch (bf16), zero-padded OOB
    for (int idx = t; idx < 594 * 4; idx += 256) {
        int r  = idx >> 2;            // 0..593 : col*66 + zz
        int kg = idx & 3;
        int col = r / 66;
        int zz  = r - col * 66;
        int gx = X + col / 3 - 1;
        int gy = Y + col % 3 - 1;
        int z  = zz - 1;
        float4 val = make_float4(0.f, 0.f, 0.f, 0.f);
        if ((unsigned)gx < (unsigned)G && (unsigned)gy < (unsigned)G &&
            (unsigned)z < (unsigned)G) {
            val = *(const float4*)(voxb +
                    ((size_t)((gx * G + gy) * G + z)) * INC + kg * 8);
        }
        int kgs = kg ^ ((zz >> 1) & 3);
        *(float4*)(&sIn[(r << 5) + (kgs << 3)]) = val;
    }
    __syncthreads();

    int w = t >> 6, l = t & 63;
    int lrow = l & 15, kg = l >> 4;
    int z0 = (w & 1) * 32;
    int n0 = (w >> 1) * 32;

    f32x4 acc[2][2];
#pragma unroll
    for (int m = 0; m < 2; m++)
#pragma unroll
        for (int nf = 0; nf < 2; nf++)
            acc[m][nf] = (f32x4){0.f, 0.f, 0.f, 0.f};

#pragma unroll
    for (int off = 0; off < 27; off++) {
        int col = off / 3;            // (dx,dy) column index 0..8
        int dz  = off % 3 - 1;

        const ushort* wp = Wt + off * 2048 + (n0 + lrow) * 32 + kg * 8;
        short8 b0 = *(const short8*)wp;
        short8 b1 = *(const short8*)(wp + 16 * 32);

#pragma unroll
        for (int m = 0; m < 2; m++) {
            int zz  = z0 + m * 16 + lrow + dz + 1;   // 0..65
            int kgs = kg ^ ((zz >> 1) & 3);
            short8 a = *(const short8*)(&sIn[((col * 66 + zz) << 5) + (kgs << 3)]);
            acc[m][0] = __builtin_amdgcn_mfma_f32_16x16x32_bf16(a, b0, acc[m][0], 0, 0, 0);
            acc[m][1] = __builtin_amdgcn_mfma_f32_16x16x32_bf16(a, b1, acc[m][1], 0, 0, 0);
        }
    }

    // ---- epilogue: C/D col=lane&15 (n), row=(lane>>4)*4+reg (z)
    size_t vbase = (size_t)(X * G + Y) * G;
#pragma unroll
    for (int m = 0; m < 2; m++)
#pragma unroll
        for (int nf = 0; nf < 2; nf++)
#pragma unroll
            for (int reg = 0; reg < 4; reg++) {
                int z = z0 + m * 16 + kg * 4 + reg;
                int n = n0 + nf * 16 + lrow;
                convo[(vbase + z) * OUTC + n] = acc[m][nf][reg];
            }
}

// ---------------------------------------------------------------------------
// Stage 4: trilinear devoxelize + residual linear (unchanged from round 4).
// ---------------------------------------------------------------------------
#define PPB 64   // points per block
#define PPW 16   // points per wave

__global__ __launch_bounds__(256) void gather_kernel(
    const float* __restrict__ pts, const float* __restrict__ feats,
    const float* __restrict__ convo, const int* __restrict__ cnts,
    const float* __restrict__ Wl, const float* __restrict__ bl,
    const int* __restrict__ sorted,
    float* __restrict__ out, int npts)
{
    __shared__ float sF[PPB][INC];    // 8 KB staged feats rows (sorted order)
    __shared__ int   sP[PPB];         // original point ids
    __shared__ float sPts[PPB][3];    // coords

    int t = threadIdx.x;

    int bid = blockIdx.x;
    int nwg = gridDim.x;
    int q = nwg >> 3, r = nwg & 7;
    int xcd = bid & 7, local = bid >> 3;
    int swz = (xcd < r) ? (xcd * (q + 1) + local)
                        : (r * (q + 1) + (xcd - r) * q + local);
    int nbase = swz * PPB;

    if (t < PPB) {
        int slot = nbase + t;
        sP[t] = (slot < npts) ? sorted[slot] : 0;
    }
    __syncthreads();

    if (t < 192) {
        int rr = t & 63, comp = t >> 6;
        sPts[rr][comp] = pts[(size_t)sP[rr] * 3 + comp];
    }
#pragma unroll
    for (int i = t; i < PPB * INC / 4; i += 256) {
        int rr = i >> 3, part = i & 7;
        ((float4*)sF[rr])[part] =
            ((const float4*)(feats + (size_t)sP[rr] * INC))[part];
    }
    __syncthreads();

    int wv = t >> 6;
    int c  = t & 63;
    float4 Wreg[8];
    const float4* wrow = (const float4*)(Wl + (size_t)c * INC);
#pragma unroll
    for (int j = 0; j < 8; j++) Wreg[j] = wrow[j];
    float bias = bl[c];

    int pbeg = wv * PPW;

    int prev_fl = -1;
    float cvm[8];   // corner values with (inb && occ) mask folded in
    float dzd[4];   // z-direction deltas

#pragma unroll 1
    for (int i = 0; i < PPW; i++) {
        int li = pbeg + i;
        int slot = nbase + li;
        int p = sP[li];
        float px = sPts[li][0];
        float py = sPts[li][1];
        float pz = sPts[li][2];
        int bx = (int)floorf(px);
        int by = (int)floorf(py);
        int bz = (int)floorf(pz);
        int flb = (bx * G + by) * G + bz;

        if (flb != prev_fl) {          // wave-uniform branch
            prev_fl = flb;
#pragma unroll
            for (int corner = 0; corner < 8; corner++) {
                int dx = (corner >> 2) & 1;
                int dy = (corner >> 1) & 1;
                int dz = corner & 1;
                int nx = bx + dx, ny = by + dy, nz = bz + dz;
                bool inb = ((unsigned)nx < (unsigned)G) &&
                           ((unsigned)ny < (unsigned)G) &&
                           ((unsigned)nz < (unsigned)G);
                int cx = min(nx, G - 1);
                int cy = min(ny, G - 1);
                int cz = min(nz, G - 1);
                int fl = (cx * G + cy) * G + cz;
                bool ok = inb && (cnts[fl] != 0);
                float v = convo[(size_t)fl * OUTC + c];
                cvm[corner] = ok ? v : 0.0f;
            }
            dzd[0] = cvm[1] - cvm[0];
            dzd[1] = cvm[3] - cvm[2];
            dzd[2] = cvm[5] - cvm[4];
            dzd[3] = cvm[7] - cvm[6];
        }

        float fx = px - (float)bx;
        float fy = py - (float)by;
        float fz = pz - (float)bz;

        float c00 = fmaf(fz, dzd[0], cvm[0]);
        float c01 = fmaf(fz, dzd[1], cvm[2]);
        float c10 = fmaf(fz, dzd[2], cvm[4]);
        float c11 = fmaf(fz, dzd[3], cvm[6]);
        float c0  = fmaf(fy, c01 - c00, c00);
        float c1  = fmaf(fy, c11 - c10, c10);
        float tri = fmaf(fx, c1 - c0, c0);

        float acc = bias + tri;

        const float4* f4 = (const float4*)sF[li];
#pragma unroll
        for (int j = 0; j < 8; j++) {
            float4 f = f4[j];
            acc += f.x * Wreg[j].x;
            acc += f.y * Wreg[j].y;
            acc += f.z * Wreg[j].z;
            acc += f.w * Wreg[j].w;
        }

        if (slot < npts)
            out[(size_t)p * OUTC + c] = acc;
    }
}

// ---------------------------------------------------------------------------
extern "C" void kernel_launch(void* const* d_in, const int* in_sizes, int n_in,
                              void* d_out, int out_size, void* d_ws, size_t ws_size,
                              hipStream_t stream)
{
    const float* pts   = (const float*)d_in[0];
    const float* feats = (const float*)d_in[1];
    const float* Wc    = (const float*)d_in[2];
    const float* Wl    = (const float*)d_in[3];
    const float* bl    = (const float*)d_in[4];
    float* out = (float*)d_out;
    int npts = in_sizes[0] / 3;
    int npts_pad = (npts + 7) & ~7;                 // 16B-align regions below

    // workspace layout (~86 MB):
    //   cnts   : NVOX int
    //   sorted : npts_pad int            (persists to gather)
    //   voxb   : NVOX*32 ushort (bf16)   (voxel means; conv input)
    //   convo  : NVOX*64 float
    //   Wt     : 27*64*32 ushort (bf16)  (transposed conv weights)
    //   cursor/chunkSums alias convo (dead until conv writes it)
    int*    cnts   = (int*)d_ws;
    int*    sorted = cnts + NVOX;
    ushort* voxb   = (ushort*)(sorted + npts_pad);
    float*  convo  = (float*)(voxb + (size_t)NVOX * INC);
    ushort* Wt     = (ushort*)(convo + (size_t)NVOX * OUTC);
    int*    cursor    = (int*)convo;                // NVOX (dies before conv)
    int*    chunkSums = cursor + NVOX;              // NCHUNK

    // zero only the counts (1 MB)
    hipMemsetAsync(cnts, 0, (size_t)NVOX * sizeof(int), stream);

    wtprep_kernel<<<216, 256, 0, stream>>>(Wc, Wt);

    int pblocks = (npts + 255) / 256;
    count_kernel<<<pblocks, 256, 0, stream>>>(pts, cnts, npts);

    scan_local_kernel<<<NCHUNK, 256, 0, stream>>>(cnts, cursor, chunkSums);
    scan_top_kernel<<<1, 256, 0, stream>>>(chunkSums);
    scan_add_kernel<<<NVOX / 256, 256, 0, stream>>>(cursor, chunkSums);
    sort_kernel<<<pblocks, 256, 0, stream>>>(pts, cursor, sorted, npts);

    voxelize_kernel<<<(NVOX * 8) / 256, 256, 0, stream>>>(cnts, cursor, sorted,
                                                          feats, voxb);

    conv_mfma_kernel<<<G * G, 256, 0, stream>>>(voxb, Wt, convo);

    int gather_blocks = (npts + PPB - 1) / PPB;
    gather_kernel<<<gather_blocks, 256, 0, stream>>>(pts, feats, convo, cnts,
                                                     Wl, bl, sorted, out, npts);
}